// Round 22
// baseline (531.654 us; speedup 1.0000x reference)
//
#include <hip/hip_runtime.h>

// MaxChamferDistance: x[16,4096,3], y[16,4096,3] f32 -> scalar f32
//
// Round-22: 8 clean nulls prove the MFMA all-pairs structure is at ITS
// ceiling (~24us mm, no pipe >35%). Algorithmic switch: uniform-grid NN.
//  - bin (32 blocks x 1024): per (dir,batch) cloud, bin the 4096 "other"
//    pts into a 24^3 grid (h=0.375, [-4.5,4.5]) fully in LDS: count ->
//    block scan -> scatter via LDS cursors. Writes offs[32][14336] (1.75MB)
//    and binned (-2p, ||p||^2) float4 (2MB) to ws.
//  - query (512 blocks x 256): one thread per own point. Expanding
//    Chebyshev shells; stop when best <= (distance to unsearched region)^2
//    -- exact: the candidate set provably contains the argmin, so min
//    equals brute force (same fma-expansion formula that passed absmax 0
//    x9). fminf is exact => scatter-order nondeterminism cannot change
//    values => replay-deterministic. Block sum -> partials -> proven
//    device-counter finale (mean/max/mean).
// ws: offs 1.75MB | binned 2MB | partials 2KB | cnt 4B  (~3.9MB < 5.25 ok)

#define BATCH 16
#define NPTS  4096
#define DB    (2 * BATCH)          // 32 (dir,batch) clouds
#define GS    24
#define NC    (GS * GS * GS)       // 13824 cells
#define NCP   14336                // offs stride per cloud (1024*14)
#define CPT   14                   // cells per thread in bin kernel
#define ORIG  (-4.5f)
#define H     0.375f
#define INVH  (1.0f / 0.375f)
#define QBLK  512                  // query blocks

static __device__ __forceinline__ int cellof(float v) {
  int c = (int)floorf((v - ORIG) * INVH);
  return min(max(c, 0), GS - 1);
}

__global__ __launch_bounds__(1024) void chamfer_bin(
    const float* __restrict__ x, const float* __restrict__ y,
    int* __restrict__ offsG, float4* __restrict__ binned,
    unsigned* __restrict__ cnt) {
  __shared__ int lcnt[NCP];        // 56 KB: counts -> starts -> cursors
  __shared__ int wbase[16];

  const int db  = blockIdx.x;      // one cloud per block
  const int tid = threadIdx.x;
  if (db == 0 && tid == 0) *cnt = 0;         // query's finale counter
  const int dir = db >> 4, b = db & 15;
  const float* other = (dir == 0 ? y : x) + (size_t)b * NPTS * 3;

  #pragma unroll
  for (int k = 0; k < CPT; ++k) lcnt[tid * CPT + k] = 0;
  __syncthreads();

  // load 4 points/thread, count into LDS
  float p0[4], p1[4], p2[4];
  int ci[4];
  #pragma unroll
  for (int k = 0; k < 4; ++k) {
    const int p = tid + k * 1024;
    p0[k] = other[p * 3 + 0];
    p1[k] = other[p * 3 + 1];
    p2[k] = other[p * 3 + 2];
    ci[k] = (cellof(p2[k]) * GS + cellof(p1[k])) * GS + cellof(p0[k]);
    atomicAdd(&lcnt[ci[k]], 1);
  }
  __syncthreads();

  // block exclusive scan over 14336 cells (14/thread serial + wave + block)
  int tsum = 0;
  #pragma unroll
  for (int k = 0; k < CPT; ++k) tsum += lcnt[tid * CPT + k];
  const int lane = tid & 63;
  int incl = tsum;
  #pragma unroll
  for (int off = 1; off < 64; off <<= 1) {
    int v = __shfl_up(incl, off, 64);
    if (lane >= off) incl += v;
  }
  const int wexcl = incl - tsum;
  if (lane == 63) wbase[tid >> 6] = incl;    // wave total
  __syncthreads();
  if (tid == 0) {
    int acc = 0;
    #pragma unroll
    for (int wv = 0; wv < 16; ++wv) {
      int t = wbase[wv]; wbase[wv] = acc; acc += t;
    }
  }
  __syncthreads();
  int start = wbase[tid >> 6] + wexcl;
  int* offsD = offsG + (size_t)db * NCP;
  #pragma unroll
  for (int k = 0; k < CPT; ++k) {
    const int c = lcnt[tid * CPT + k];
    lcnt[tid * CPT + k] = start;             // LDS: cell start (cursor)
    offsD[tid * CPT + k] = start;            // global: pristine offsets
    start += c;                              // sentinel lands at cell NC
  }
  __syncthreads();

  // scatter transformed points via LDS cursors
  float4* bd = binned + (size_t)db * NPTS;
  #pragma unroll
  for (int k = 0; k < 4; ++k) {
    const int slot = atomicAdd(&lcnt[ci[k]], 1);
    const float w = fmaf(p2[k], p2[k], fmaf(p1[k], p1[k], p0[k] * p0[k]));
    bd[slot] = make_float4(-2.f * p0[k], -2.f * p1[k], -2.f * p2[k], w);
  }
}

__global__ __launch_bounds__(256) void chamfer_query(
    const float* __restrict__ x, const float* __restrict__ y,
    const int* __restrict__ offsG, const float4* __restrict__ binned,
    float* __restrict__ partials, unsigned* __restrict__ cnt,
    float* __restrict__ out) {
  __shared__ float red[4];
  __shared__ float dls[DB];
  __shared__ int isLast;

  const int bid = blockIdx.x;      // 512 = 32 db x 16 chunks of 256 pts
  const int tid = threadIdx.x;
  const int db  = bid >> 4;
  const int i   = (bid & 15) * 256 + tid;
  const int dir = db >> 4, b = db & 15;
  const float* own = (dir == 0 ? x : y) + (size_t)b * NPTS * 3;

  const float qx = own[i * 3 + 0];
  const float qy = own[i * 3 + 1];
  const float qz = own[i * 3 + 2];
  const float sq = fmaf(qz, qz, fmaf(qy, qy, qx * qx));
  const int cx = cellof(qx), cy = cellof(qy), cz = cellof(qz);
  const int* offs = offsG + (size_t)db * NCP;
  const float4* bd = binned + (size_t)db * NPTS;

  float dmin = 1e30f;
  for (int s = 0; s < GS; ++s) {
    const int zlo = max(cz - s, 0), zhi = min(cz + s, GS - 1);
    const int ylo = max(cy - s, 0), yhi = min(cy + s, GS - 1);
    const int xlo = max(cx - s, 0), xhi = min(cx + s, GS - 1);
    for (int zz = zlo; zz <= zhi; ++zz)
      for (int yy = ylo; yy <= yhi; ++yy)
        for (int xx = xlo; xx <= xhi; ++xx) {
          const int ch = max(max(abs(zz - cz), abs(yy - cy)), abs(xx - cx));
          if (ch != s) continue;             // interior already searched
          const int cell = (zz * GS + yy) * GS + xx;
          const int st = offs[cell], en = offs[cell + 1];
          for (int t = st; t < en; ++t) {
            const float4 q4 = bd[t];
            const float d = fmaf(q4.x, qx,
                            fmaf(q4.y, qy,
                            fmaf(q4.z, qz, q4.w)));
            dmin = fminf(dmin, d);
          }
        }
    // distance from q to the unsearched region (outside the s-box)
    float bnd = 1e30f;
    if (cx - s > 0)      bnd = fminf(bnd, qx - (ORIG + (cx - s) * H));
    if (cx + s < GS - 1) bnd = fminf(bnd, (ORIG + (cx + s + 1) * H) - qx);
    if (cy - s > 0)      bnd = fminf(bnd, qy - (ORIG + (cy - s) * H));
    if (cy + s < GS - 1) bnd = fminf(bnd, (ORIG + (cy + s + 1) * H) - qy);
    if (cz - s > 0)      bnd = fminf(bnd, qz - (ORIG + (cz - s) * H));
    if (cz + s < GS - 1) bnd = fminf(bnd, (ORIG + (cz + s + 1) * H) - qz);
    if (bnd >= 1e29f) break;                 // searched the whole grid
    if (sq + dmin <= bnd * bnd) break;       // cannot be beaten outside
  }
  float v = sq + dmin;                       // exact-f32 ||x||^2 fold

  // block sum (fixed order)
  #pragma unroll
  for (int off = 32; off > 0; off >>= 1) v += __shfl_down(v, off, 64);
  if ((tid & 63) == 0) red[tid >> 6] = v;
  __syncthreads();
  if (tid == 0) {
    partials[bid] = (red[0] + red[1]) + (red[2] + red[3]);
    __threadfence();
    unsigned old = __hip_atomic_fetch_add(cnt, 1u, __ATOMIC_ACQ_REL,
                                          __HIP_MEMORY_SCOPE_AGENT);
    isLast = (old == QBLK - 1);
  }
  __syncthreads();

  // last block: mean over points, max over directions, mean over batch
  if (isLast) {
    __threadfence();
    if (tid < DB) {
      float s = 0.0f;
      #pragma unroll
      for (int j = 0; j < 16; ++j) {
        unsigned uv = __hip_atomic_load(
            (const unsigned*)&partials[tid * 16 + j], __ATOMIC_RELAXED,
            __HIP_MEMORY_SCOPE_AGENT);
        s += __uint_as_float(uv);
      }
      dls[tid] = s * (1.0f / (float)NPTS);
    }
    __syncthreads();
    if (tid < BATCH) {
      float mx = fmaxf(dls[tid], dls[tid + BATCH]);
      #pragma unroll
      for (int off = 8; off > 0; off >>= 1) mx += __shfl_down(mx, off, 16);
      if (tid == 0) out[0] = mx * (1.0f / (float)BATCH);
    }
  }
}

extern "C" void kernel_launch(void* const* d_in, const int* in_sizes, int n_in,
                              void* d_out, int out_size, void* d_ws, size_t ws_size,
                              hipStream_t stream) {
  const float* x = (const float*)d_in[0];
  const float* y = (const float*)d_in[1];
  float* out = (float*)d_out;

  int* offsG      = (int*)d_ws;                              // 1.75 MB
  float4* binned  = (float4*)((char*)d_ws + (size_t)DB * NCP * 4);  // 2 MB
  float* partials = (float*)((char*)binned + (size_t)DB * NPTS * 16);
  unsigned* cnt   = (unsigned*)(partials + QBLK);

  chamfer_bin<<<DB, 1024, 0, stream>>>(x, y, offsG, binned, cnt);
  chamfer_query<<<QBLK, 256, 0, stream>>>(x, y, offsG, binned,
                                          partials, cnt, out);
}

// Round 23
// 68.192 us; speedup vs baseline: 7.7964x; 7.7964x over previous
//
#include <hip/hip_runtime.h>

// MaxChamferDistance: x[16,4096,3], y[16,4096,3] f32 -> scalar f32
//
// Round-23: grid-NN regressed 18x (divergence); MFMA champion restored.
// mm compute = r12/r20 verbatim (29.5us, absmax 0 x10). One change: the
// combine kernel is folded into mm as a per-db tail -- last-of-16 blocks
// per db (acq-rel counter, r8/r16-proven pattern) min-merges that db's two
// gm halves and computes dist[db]; last db overall folds max/mean -> out.
// Removes the second launch + graph drain (~3.5-4us). All folded values are
// fixed-order arithmetic => replay-deterministic. Counters pre-zeroed by a
// 136B hipMemsetAsync (graph-safe).

typedef __attribute__((ext_vector_type(8)))  short bf16x8;
typedef __attribute__((ext_vector_type(16))) float f32x16;

#define BATCH   16
#define NPTS    4096
#define DB      (2 * BATCH)            // 32 (dir,batch)
#define GM_F32  (2 * DB * NPTS)        // 262144 f32 = 1 MB

static __device__ __forceinline__ unsigned bf16rn(float f) {
  unsigned u = __float_as_uint(f);
  return (u + 0x7FFFu + ((u >> 16) & 1u)) >> 16;   // round-to-nearest-even
}
static __device__ __forceinline__ float bf2f(unsigned h) {
  return __uint_as_float(h << 16);
}
static __device__ __forceinline__ unsigned pk(unsigned lo, unsigned hi) {
  return (lo & 0xFFFFu) | (hi << 16);
}

__global__ __launch_bounds__(512) void chamfer_mm(
    const float* __restrict__ x, const float* __restrict__ y,
    float* __restrict__ gm, float* __restrict__ dist,
    unsigned* __restrict__ dbcnt, unsigned* __restrict__ gcnt,
    float* __restrict__ out) {
  // 64 m-tiles x 64 uint4 (tile layout: [kh(2)][row(32)]) = 64 KB
  __shared__ __align__(16) uint4 afl[64 * 64];
  __shared__ float red2[8];
  __shared__ int amLastDb, amLastAll;

  const int bid = blockIdx.x;          // 512 = 32 db x 8 own-chunks x 2 halves
  const int tid = threadIdx.x;

  const int db  = bid >> 4;
  const int r   = bid & 15;
  const int c   = r >> 1;              // own chunk [0,8)
  const int h   = r & 1;               // m-half
  const int dir = db >> 4, b = db & 15;
  const float* own   = (dir == 0 ? x : y) + (size_t)b * NPTS * 3;
  const float* other = (dir == 0 ? y : x) + (size_t)b * NPTS * 3;
  const float* mp    = other + (size_t)h * 2048 * 3;

  // ---- stage: convert 2048 other pts -> A-frags in LDS (4 pts/thread) ----
  #pragma unroll
  for (int k = 0; k < 4; ++k) {
    const int p = tid + k * 512;       // [0,2048)
    float y0 = mp[p * 3 + 0], y1 = mp[p * 3 + 1], y2 = mp[p * 3 + 2];
    float wv = fmaf(y2, y2, fmaf(y1, y1, y0 * y0));
    float z0 = -2.f * y0, z1 = -2.f * y1, z2 = -2.f * y2;
    unsigned h0 = bf16rn(z0), h1 = bf16rn(z1), h2 = bf16rn(z2);
    unsigned e0 = bf16rn(z0 - bf2f(h0));
    unsigned e1 = bf16rn(z1 - bf2f(h1));
    unsigned e2 = bf16rn(z2 - bf2f(h2));
    unsigned wh = bf16rn(wv), wl = bf16rn(wv - bf2f(wh));
    const int tile = p >> 5, row = p & 31;
    afl[tile * 64 + row]      =
        make_uint4(pk(h0, h1), pk(h2, e0), pk(e1, e2), pk(h0, h1)); // K0-7
    afl[tile * 64 + 32 + row] =
        make_uint4(pk(h2, wh), pk(wl, 0u), 0u, 0u);                 // K8-15
  }

  // ---- resident B-frags: 64 own pts per wave (2 n-tiles of 32) ----------
  const int w = tid >> 6, l = tid & 63;
  const int col = l & 31, kh = l >> 5;
  const unsigned ONE = 0x3F80u;
  bf16x8 bfr[2];
  float sq[2], rmn[2];
  #pragma unroll
  for (int nt = 0; nt < 2; ++nt) {
    const int n = c * 512 + w * 64 + nt * 32 + col;
    float a0 = own[n * 3 + 0], a1 = own[n * 3 + 1], a2 = own[n * 3 + 2];
    sq[nt]  = fmaf(a2, a2, fmaf(a1, a1, a0 * a0));   // exact f32, added last
    rmn[nt] = 1e30f;
    unsigned h0 = bf16rn(a0), h1 = bf16rn(a1), h2 = bf16rn(a2);
    unsigned e0 = bf16rn(a0 - bf2f(h0));
    unsigned e1 = bf16rn(a1 - bf2f(h1));
    unsigned e2 = bf16rn(a2 - bf2f(h2));
    union { unsigned uu[4]; bf16x8 v; } U;
    U.uu[0] = (kh == 0) ? pk(h0, h1) : pk(e2, ONE);
    U.uu[1] = (kh == 0) ? pk(h2, h0) : pk(ONE, 0u);
    U.uu[2] = (kh == 0) ? pk(h1, h2) : 0u;
    U.uu[3] = (kh == 0) ? pk(e0, e1) : 0u;
    bfr[nt] = U.v;
  }
  __syncthreads();

  // ---- main loop: 64 tiles x [1 ds_read_b128 + 2 MFMA + min3 tree] ------
  const int aoff = kh * 32 + col;      // lane's uint4 index within a tile
  const f32x16 z16 = {0.f, 0.f, 0.f, 0.f, 0.f, 0.f, 0.f, 0.f,
                      0.f, 0.f, 0.f, 0.f, 0.f, 0.f, 0.f, 0.f};
  #pragma unroll 4
  for (int mt = 0; mt < 64; ++mt) {
    union { uint4 u; bf16x8 v; } A;
    A.u = afl[mt * 64 + aoff];
    #pragma unroll
    for (int nt = 0; nt < 2; ++nt) {
      f32x16 acc = __builtin_amdgcn_mfma_f32_32x32x16_bf16(
          A.v, bfr[nt], z16, 0, 0, 0);
      float m0 = fminf(fminf(acc[0],  acc[1]),  acc[2]);   // v_min3 chains
      float m1 = fminf(fminf(acc[3],  acc[4]),  acc[5]);
      float m2 = fminf(fminf(acc[6],  acc[7]),  acc[8]);
      float m3 = fminf(fminf(acc[9],  acc[10]), acc[11]);
      float m4 = fminf(fminf(acc[12], acc[13]), acc[14]);
      float m5 = fminf(fminf(acc[15], m0), m1);
      float m6 = fminf(fminf(m2, m3), m4);
      rmn[nt] = fminf(fminf(m5, m6), rmn[nt]);
    }
  }

  // ---- epilogue: rows live in both lane halves -> fold lane^32 ----------
  #pragma unroll
  for (int nt = 0; nt < 2; ++nt) {
    float v = fminf(rmn[nt], __shfl_xor(rmn[nt], 32, 64));
    float sv = v + sq[nt];
    if (l < 32)
      gm[(size_t)(h * DB + db) * NPTS + c * 512 + w * 64 + nt * 32 + col] = sv;
  }

  // ---- per-db tail combine: last of this db's 16 blocks ------------------
  if (tid == 0) {
    __threadfence();                                 // release gm slice
    unsigned old = __hip_atomic_fetch_add(&dbcnt[db], 1u, __ATOMIC_ACQ_REL,
                                          __HIP_MEMORY_SCOPE_AGENT);
    amLastDb = (old == 15);
  }
  __syncthreads();                                   // amLastDb block-uniform
  if (amLastDb) {
    __threadfence();                                 // acquire side
    const unsigned* g0 = (const unsigned*)(gm + (size_t)db * NPTS);
    const unsigned* g1 = (const unsigned*)(gm + (size_t)(DB + db) * NPTS);
    float s = 0.0f;
    #pragma unroll
    for (int i = tid; i < NPTS; i += 512) {
      float v0 = __uint_as_float(__hip_atomic_load(
          &g0[i], __ATOMIC_RELAXED, __HIP_MEMORY_SCOPE_AGENT));
      float v1 = __uint_as_float(__hip_atomic_load(
          &g1[i], __ATOMIC_RELAXED, __HIP_MEMORY_SCOPE_AGENT));
      s += fminf(v0, v1);
    }
    #pragma unroll
    for (int off = 32; off > 0; off >>= 1) s += __shfl_down(s, off, 64);
    if (l == 0) red2[w] = s;
    __syncthreads();
    if (tid == 0) {
      float t = 0.0f;
      #pragma unroll
      for (int k2 = 0; k2 < 8; ++k2) t += red2[k2];
      dist[db] = t * (1.0f / (float)NPTS);
      __threadfence();                               // release dist[db]
      unsigned o2 = __hip_atomic_fetch_add(gcnt, 1u, __ATOMIC_ACQ_REL,
                                           __HIP_MEMORY_SCOPE_AGENT);
      amLastAll = (o2 == DB - 1);
    }
    __syncthreads();                                 // amLastAll uniform
    if (amLastAll) {
      __threadfence();                               // acquire side
      if (tid < BATCH) {
        float d0 = __uint_as_float(__hip_atomic_load(
            (const unsigned*)&dist[tid], __ATOMIC_RELAXED,
            __HIP_MEMORY_SCOPE_AGENT));
        float d1 = __uint_as_float(__hip_atomic_load(
            (const unsigned*)&dist[tid + BATCH], __ATOMIC_RELAXED,
            __HIP_MEMORY_SCOPE_AGENT));
        float mx = fmaxf(d0, d1);
        #pragma unroll
        for (int off = 8; off > 0; off >>= 1) mx += __shfl_down(mx, off, 16);
        if (tid == 0) out[0] = mx * (1.0f / (float)BATCH);
      }
    }
  }
}

extern "C" void kernel_launch(void* const* d_in, const int* in_sizes, int n_in,
                              void* d_out, int out_size, void* d_ws, size_t ws_size,
                              hipStream_t stream) {
  const float* x = (const float*)d_in[0];
  const float* y = (const float*)d_in[1];
  float* out = (float*)d_out;

  float* gm       = (float*)d_ws;                  // 1 MB
  float* dist     = gm + GM_F32;                   // 32 f32
  unsigned* dbcnt = (unsigned*)(dist + DB);        // 32 u32
  unsigned* gcnt  = dbcnt + DB;                    // 1 u32

  hipMemsetAsync(dbcnt, 0, (DB + 1) * sizeof(unsigned), stream);
  chamfer_mm<<<512, 512, 0, stream>>>(x, y, gm, dist, dbcnt, gcnt, out);
}

// Round 24
// 29.992 us; speedup vs baseline: 17.7264x; 2.2737x over previous
//
#include <hip/hip_runtime.h>

// MaxChamferDistance: x[16,4096,3], y[16,4096,3] f32 -> scalar f32
//
// FINAL (round-24): champion restore = r20 verbatim (29.55us, absmax 0).
// History: fp32-VALU ladder 113->52us (rounds 1-9, exhausted at ~85% of the
// 3-fma/pair VALU roofline); MFMA K=11 bf16 hi/lo-split GEMM w/ fused min
// 52->29.5us (rounds 10-12,20). The mm loop's ~24us is invariant across 9
// cleanly-tested scheduling axes (occupancy, ILP, min structure, LDS size,
// prefetch, acc order, setprio, reg bounds, launch fusion); grid-NN loses
// 18x to divergence; fused-tail combine loses 2.3x to tail serialization.
// Numerics: A=[ybh(3),ybl(3),ybh(3),wh,wl], B=[xh(3),xh(3),xl(3),1,1]
// => acc = ||y||^2-2<x,y>+O(1e-4); exact-f32 ||x||^2 added post-min.
// All reductions fixed-order; atomic counter gates only WHO folds (values
// order-independent) => replay-deterministic.

typedef __attribute__((ext_vector_type(8)))  short bf16x8;
typedef __attribute__((ext_vector_type(16))) float f32x16;

#define BATCH   16
#define NPTS    4096
#define DB      (2 * BATCH)            // 32 (dir,batch)
#define GM_F32  (2 * DB * NPTS)        // 262144 f32 = 1 MB

static __device__ __forceinline__ unsigned bf16rn(float f) {
  unsigned u = __float_as_uint(f);
  return (u + 0x7FFFu + ((u >> 16) & 1u)) >> 16;   // round-to-nearest-even
}
static __device__ __forceinline__ float bf2f(unsigned h) {
  return __uint_as_float(h << 16);
}
static __device__ __forceinline__ unsigned pk(unsigned lo, unsigned hi) {
  return (lo & 0xFFFFu) | (hi << 16);
}

__global__ __launch_bounds__(512) void chamfer_mm(
    const float* __restrict__ x, const float* __restrict__ y,
    float* __restrict__ gm, unsigned* __restrict__ cnt) {
  // 64 m-tiles x 64 uint4 (tile layout: [kh(2)][row(32)]) = 64 KB
  __shared__ __align__(16) uint4 afl[64 * 64];

  const int bid = blockIdx.x;          // 512 = 32 db x 8 own-chunks x 2 halves
  const int tid = threadIdx.x;
  if (bid == 0 && tid == 0) *cnt = 0;  // combine's counter (stream-ordered)

  const int db  = bid >> 4;
  const int r   = bid & 15;
  const int c   = r >> 1;              // own chunk [0,8)
  const int h   = r & 1;               // m-half
  const int dir = db >> 4, b = db & 15;
  const float* own   = (dir == 0 ? x : y) + (size_t)b * NPTS * 3;
  const float* other = (dir == 0 ? y : x) + (size_t)b * NPTS * 3;
  const float* mp    = other + (size_t)h * 2048 * 3;

  // ---- stage: convert 2048 other pts -> A-frags in LDS (4 pts/thread) ----
  #pragma unroll
  for (int k = 0; k < 4; ++k) {
    const int p = tid + k * 512;       // [0,2048)
    float y0 = mp[p * 3 + 0], y1 = mp[p * 3 + 1], y2 = mp[p * 3 + 2];
    float wv = fmaf(y2, y2, fmaf(y1, y1, y0 * y0));
    float z0 = -2.f * y0, z1 = -2.f * y1, z2 = -2.f * y2;
    unsigned h0 = bf16rn(z0), h1 = bf16rn(z1), h2 = bf16rn(z2);
    unsigned e0 = bf16rn(z0 - bf2f(h0));
    unsigned e1 = bf16rn(z1 - bf2f(h1));
    unsigned e2 = bf16rn(z2 - bf2f(h2));
    unsigned wh = bf16rn(wv), wl = bf16rn(wv - bf2f(wh));
    const int tile = p >> 5, row = p & 31;
    afl[tile * 64 + row]      =
        make_uint4(pk(h0, h1), pk(h2, e0), pk(e1, e2), pk(h0, h1)); // K0-7
    afl[tile * 64 + 32 + row] =
        make_uint4(pk(h2, wh), pk(wl, 0u), 0u, 0u);                 // K8-15
  }

  // ---- resident B-frags: 64 own pts per wave (2 n-tiles of 32) ----------
  const int w = tid >> 6, l = tid & 63;
  const int col = l & 31, kh = l >> 5;
  const unsigned ONE = 0x3F80u;
  bf16x8 bfr[2];
  float sq[2], rmn[2];
  #pragma unroll
  for (int nt = 0; nt < 2; ++nt) {
    const int n = c * 512 + w * 64 + nt * 32 + col;
    float a0 = own[n * 3 + 0], a1 = own[n * 3 + 1], a2 = own[n * 3 + 2];
    sq[nt]  = fmaf(a2, a2, fmaf(a1, a1, a0 * a0));   // exact f32, added last
    rmn[nt] = 1e30f;
    unsigned h0 = bf16rn(a0), h1 = bf16rn(a1), h2 = bf16rn(a2);
    unsigned e0 = bf16rn(a0 - bf2f(h0));
    unsigned e1 = bf16rn(a1 - bf2f(h1));
    unsigned e2 = bf16rn(a2 - bf2f(h2));
    union { unsigned uu[4]; bf16x8 v; } U;
    U.uu[0] = (kh == 0) ? pk(h0, h1) : pk(e2, ONE);
    U.uu[1] = (kh == 0) ? pk(h2, h0) : pk(ONE, 0u);
    U.uu[2] = (kh == 0) ? pk(h1, h2) : 0u;
    U.uu[3] = (kh == 0) ? pk(e0, e1) : 0u;
    bfr[nt] = U.v;
  }
  __syncthreads();

  // ---- main loop: 64 tiles x [1 ds_read_b128 + 2 MFMA + min3 tree] ------
  const int aoff = kh * 32 + col;      // lane's uint4 index within a tile
  const f32x16 z16 = {0.f, 0.f, 0.f, 0.f, 0.f, 0.f, 0.f, 0.f,
                      0.f, 0.f, 0.f, 0.f, 0.f, 0.f, 0.f, 0.f};
  #pragma unroll 4
  for (int mt = 0; mt < 64; ++mt) {
    union { uint4 u; bf16x8 v; } A;
    A.u = afl[mt * 64 + aoff];
    #pragma unroll
    for (int nt = 0; nt < 2; ++nt) {
      f32x16 acc = __builtin_amdgcn_mfma_f32_32x32x16_bf16(
          A.v, bfr[nt], z16, 0, 0, 0);
      float m0 = fminf(fminf(acc[0],  acc[1]),  acc[2]);   // v_min3 chains
      float m1 = fminf(fminf(acc[3],  acc[4]),  acc[5]);
      float m2 = fminf(fminf(acc[6],  acc[7]),  acc[8]);
      float m3 = fminf(fminf(acc[9],  acc[10]), acc[11]);
      float m4 = fminf(fminf(acc[12], acc[13]), acc[14]);
      float m5 = fminf(fminf(acc[15], m0), m1);
      float m6 = fminf(fminf(m2, m3), m4);
      rmn[nt] = fminf(fminf(m5, m6), rmn[nt]);
    }
  }

  // ---- epilogue: rows live in both lane halves -> fold lane^32 ----------
  #pragma unroll
  for (int nt = 0; nt < 2; ++nt) {
    float v = fminf(rmn[nt], __shfl_xor(rmn[nt], 32, 64));
    float sv = v + sq[nt];
    if (l < 32)
      gm[(size_t)(h * DB + db) * NPTS + c * 512 + w * 64 + nt * 32 + col] = sv;
  }
}

// 32 blocks: min over halves + per-db mean; last block folds max/mean -> out.
__global__ __launch_bounds__(256) void chamfer_combine(
    const float* __restrict__ gm, float* __restrict__ dist,
    unsigned* __restrict__ cnt, float* __restrict__ out) {
  const int db = blockIdx.x;
  const float* g0 = gm + (size_t)db * NPTS;
  const float* g1 = gm + (size_t)(DB + db) * NPTS;
  float s = 0.0f;
  for (int i = threadIdx.x; i < NPTS; i += 256)
    s += fminf(g0[i], g1[i]);
  #pragma unroll
  for (int off = 32; off > 0; off >>= 1) s += __shfl_down(s, off, 64);
  __shared__ float red[4];
  const int lane = threadIdx.x & 63, wid = threadIdx.x >> 6;
  if (lane == 0) red[wid] = s;
  __syncthreads();
  if (threadIdx.x == 0) {
    dist[db] = ((red[0] + red[1]) + (red[2] + red[3])) * (1.0f / (float)NPTS);
    __threadfence();
    unsigned old = __hip_atomic_fetch_add(cnt, 1u, __ATOMIC_ACQ_REL,
                                          __HIP_MEMORY_SCOPE_AGENT);
    if (old == DB - 1) {
      __threadfence();
      float acc = 0.0f;
      #pragma unroll
      for (int b = 0; b < BATCH; ++b) {
        float d0 = __uint_as_float(__hip_atomic_load(
            (const unsigned*)&dist[b], __ATOMIC_RELAXED,
            __HIP_MEMORY_SCOPE_AGENT));
        float d1 = __uint_as_float(__hip_atomic_load(
            (const unsigned*)&dist[b + BATCH], __ATOMIC_RELAXED,
            __HIP_MEMORY_SCOPE_AGENT));
        acc += fmaxf(d0, d1);
      }
      out[0] = acc * (1.0f / (float)BATCH);
    }
  }
}

extern "C" void kernel_launch(void* const* d_in, const int* in_sizes, int n_in,
                              void* d_out, int out_size, void* d_ws, size_t ws_size,
                              hipStream_t stream) {
  const float* x = (const float*)d_in[0];
  const float* y = (const float*)d_in[1];
  float* out = (float*)d_out;

  float* gm     = (float*)d_ws;                    // 1 MB
  float* dist   = gm + GM_F32;                     // 32 f32
  unsigned* cnt = (unsigned*)(dist + DB);          // 1 u32

  chamfer_mm<<<512, 512, 0, stream>>>(x, y, gm, cnt);
  chamfer_combine<<<DB, 256, 0, stream>>>(gm, dist, cnt, out);
}